// Round 1
// baseline (738.593 us; speedup 1.0000x reference)
//
#include <hip/hip_runtime.h>
#include <hip/hip_bf16.h>
#include <math.h>

// SelfAttentionLayer: B=8,S=2048,D_IN=D_HID=D_OUT=1024 (fp32 interface).
// Pipeline (all bf16 MFMA GEMMs, fp32 accumulate, fp32 residual+LN):
//   1) cast x, Wq, Wk, Wv, Wo -> bf16
//   2) Q  = x@Wq^T + bq            (gemm_bt, bias over cols)
//   3) K  = x@Wk^T + bk
//   4) VT = Wv@x^T + bv            (V stored transposed [H, B*S] -> every GEMM is B^T-form)
//   5) S  = Q@K^T * 1/32           (batched, bf16 scores)
//   6) softmax rows in place
//   7) AO = P@V = P@VT^T           (batched; overwrites Q buffer)
//   8) pre = AO@Wo^T + bo          (fp32 out, into scores buffer)
//   9) out = LayerNorm(pre + x)*gamma + beta   (fp32)
//
// ws layout (bytes):          need 209,715,200 total
//   [0,32M)    xb   bf16 [16384,1024]
//   [32M,64M)  Qb   bf16 [16384,1024]   (reused as AO after scores)
//   [64M,96M)  Kb   bf16 [16384,1024]
//   [96M,128M) VT   bf16 [1024, 16384]  (per-batch slice: cols b*2048..)
//   [128M,192M)Sb   bf16 [8,2048,2048]  (reused as fp32 preLN [16384,1024])
//   [192M,200M)Wqb/Wkb/Wvb/Wob bf16 1M elems each

typedef __bf16 bf16;
typedef __attribute__((ext_vector_type(8))) __bf16 bf16x8;
typedef __attribute__((ext_vector_type(4))) __bf16 bf16x4;
typedef __attribute__((ext_vector_type(4))) float f32x4;

__device__ __forceinline__ void async16(const bf16* g, bf16* l) {
    __builtin_amdgcn_global_load_lds(
        (const __attribute__((address_space(1))) void*)g,
        (__attribute__((address_space(3))) void*)l, 16, 0, 0);
}

__global__ __launch_bounds__(256) void cast_f32_bf16(
    const float* __restrict__ in, bf16* __restrict__ out, int n)
{
    int i = (blockIdx.x * 256 + threadIdx.x) * 4;
    if (i >= n) return;
    float4 v = *(const float4*)(in + i);
    bf16x4 o = { (bf16)v.x, (bf16)v.y, (bf16)v.z, (bf16)v.w };
    *(bf16x4*)(out + i) = o;
}

// C[m,n] = scale * sum_k A[m,k]*B[n,k] + bias;  A:[M,K] lda, B:[N,K] ldb (both bf16).
// bias_mode: 0 none, 1 bias[n], 2 bias[m]. c_fp32: store fp32 else bf16.
// grid: (N/128, M/128, batches); 256 threads = 4 waves, each wave 64x64 quadrant.
__global__ __launch_bounds__(256) void gemm_bt(
    const bf16* __restrict__ A, long lda, long sA,
    const bf16* __restrict__ B, long ldb, long sB,
    void* __restrict__ Cv, long ldc, long sC,
    const float* __restrict__ bias, int bias_mode,
    float scale, int c_fp32, int K)
{
    __shared__ bf16 lA[128 * 32];   // 8 KB, row-major [m][k], no pad (global_load_lds layout)
    __shared__ bf16 lB[128 * 32];   // 8 KB, [n][k]

    const int tid = threadIdx.x;
    const long tM = (long)blockIdx.y * 128;
    const long tN = (long)blockIdx.x * 128;
    A += (long)blockIdx.z * sA;
    B += (long)blockIdx.z * sB;

    // staging: thread -> (row = tid/4, 16B chunk tid%4); lds byte offset = tid*16 (wave-contig)
    const int ra = tid >> 2;
    const int c8 = (tid & 3) * 8;
    const bf16* ga0 = A + (tM + ra) * lda + c8;
    const bf16* ga1 = ga0 + 64 * lda;
    const bf16* gb0 = B + (tN + ra) * ldb + c8;
    const bf16* gb1 = gb0 + 64 * ldb;
    bf16* la0 = lA + ra * 32 + c8;
    bf16* la1 = la0 + 64 * 32;
    bf16* lb0 = lB + ra * 32 + c8;
    bf16* lb1 = lb0 + 64 * 32;

    const int w = tid >> 6, lane = tid & 63;
    const int wm = (w & 1) * 64, wn = (w >> 1) * 64;
    const int quad = lane >> 4, lr = lane & 15;

    f32x4 acc[4][4] = {};

    for (int k0 = 0; k0 < K; k0 += 32) {
        async16(ga0 + k0, la0);
        async16(ga1 + k0, la1);
        async16(gb0 + k0, lb0);
        async16(gb1 + k0, lb1);
        __syncthreads();   // compiler emits vmcnt(0) drain before barrier

        bf16x8 af[4], bfr[4];
#pragma unroll
        for (int i = 0; i < 4; i++)
            af[i] = *(const bf16x8*)&lA[(wm + i * 16 + lr) * 32 + quad * 8];
#pragma unroll
        for (int j = 0; j < 4; j++)
            bfr[j] = *(const bf16x8*)&lB[(wn + j * 16 + lr) * 32 + quad * 8];
#pragma unroll
        for (int i = 0; i < 4; i++)
#pragma unroll
            for (int j = 0; j < 4; j++)
                acc[i][j] = __builtin_amdgcn_mfma_f32_16x16x32_bf16(
                    af[i], bfr[j], acc[i][j], 0, 0, 0);
        __syncthreads();   // protect LDS from next iteration's staging
    }

    // epilogue: C/D layout col=lane&15, row=(lane>>4)*4+reg  [verified m89/m91]
    if (c_fp32) {
        float* C = (float*)Cv + (long)blockIdx.z * sC;
#pragma unroll
        for (int i = 0; i < 4; i++) {
#pragma unroll
            for (int r = 0; r < 4; r++) {
                const long gm = tM + wm + i * 16 + quad * 4 + r;
                const float bm = (bias_mode == 2) ? bias[gm] : 0.0f;
                float* crow = C + gm * ldc + tN + wn;
#pragma unroll
                for (int j = 0; j < 4; j++) {
                    const long gn = wn + j * 16 + lr;
                    float v = acc[i][j][r] * scale + bm;
                    if (bias_mode == 1) v += bias[tN + gn];
                    crow[j * 16 + lr] = v;
                }
            }
        }
    } else {
        bf16* C = (bf16*)Cv + (long)blockIdx.z * sC;
#pragma unroll
        for (int i = 0; i < 4; i++) {
#pragma unroll
            for (int r = 0; r < 4; r++) {
                const long gm = tM + wm + i * 16 + quad * 4 + r;
                const float bm = (bias_mode == 2) ? bias[gm] : 0.0f;
                bf16* crow = C + gm * ldc + tN + wn;
#pragma unroll
                for (int j = 0; j < 4; j++) {
                    const long gn = wn + j * 16 + lr;
                    float v = acc[i][j][r] * scale + bm;
                    if (bias_mode == 1) v += bias[tN + gn];
                    crow[j * 16 + lr] = (bf16)v;
                }
            }
        }
    }
}

// in-place softmax over rows of 2048 bf16; one block (4 waves) per row
__global__ __launch_bounds__(256) void softmax2048(bf16* __restrict__ S)
{
    const long row = blockIdx.x;
    bf16* p = S + row * 2048;
    const int t = threadIdx.x;

    bf16x8 v = *(const bf16x8*)(p + t * 8);
    float f[8];
    float m = -3.0e38f;
#pragma unroll
    for (int i = 0; i < 8; i++) { f[i] = (float)v[i]; m = fmaxf(m, f[i]); }
    for (int o = 32; o; o >>= 1) m = fmaxf(m, __shfl_down(m, o));

    __shared__ float sm[4], ssum[4];
    if ((t & 63) == 0) sm[t >> 6] = m;
    __syncthreads();
    m = fmaxf(fmaxf(sm[0], sm[1]), fmaxf(sm[2], sm[3]));

    float s = 0.0f;
#pragma unroll
    for (int i = 0; i < 8; i++) { f[i] = __expf(f[i] - m); s += f[i]; }
    for (int o = 32; o; o >>= 1) s += __shfl_down(s, o);
    if ((t & 63) == 0) ssum[t >> 6] = s;
    __syncthreads();
    s = ssum[0] + ssum[1] + ssum[2] + ssum[3];

    const float inv = 1.0f / s;
    bf16x8 ov;
#pragma unroll
    for (int i = 0; i < 8; i++) ov[i] = (bf16)(f[i] * inv);
    *(bf16x8*)(p + t * 8) = ov;
}

// out = LN(pre + x) * gamma + beta over rows of 1024 fp32; one block per row
__global__ __launch_bounds__(256) void ln_res(
    const float* __restrict__ pre, const float* __restrict__ x,
    const float* __restrict__ gamma, const float* __restrict__ beta,
    float* __restrict__ out)
{
    const long row = blockIdx.x;
    const int t = threadIdx.x;
    const long base = row * 1024 + t * 4;

    float4 a = *(const float4*)(pre + base);
    float4 b = *(const float4*)(x + base);
    float v0 = a.x + b.x, v1 = a.y + b.y, v2 = a.z + b.z, v3 = a.w + b.w;

    float s = v0 + v1 + v2 + v3;
    float q = v0 * v0 + v1 * v1 + v2 * v2 + v3 * v3;
    for (int o = 32; o; o >>= 1) { s += __shfl_down(s, o); q += __shfl_down(q, o); }

    __shared__ float ls[4], lq[4];
    if ((t & 63) == 0) { ls[t >> 6] = s; lq[t >> 6] = q; }
    __syncthreads();
    s = ls[0] + ls[1] + ls[2] + ls[3];
    q = lq[0] + lq[1] + lq[2] + lq[3];

    const float mean = s * (1.0f / 1024.0f);
    const float var = q * (1.0f / 1024.0f) - mean * mean;
    const float rstd = rsqrtf(var + 1e-5f);

    const int c = t * 4;
    float4 g = *(const float4*)(gamma + c);
    float4 be = *(const float4*)(beta + c);
    float4 o;
    o.x = (v0 - mean) * rstd * g.x + be.x;
    o.y = (v1 - mean) * rstd * g.y + be.y;
    o.z = (v2 - mean) * rstd * g.z + be.z;
    o.w = (v3 - mean) * rstd * g.w + be.w;
    *(float4*)(out + base) = o;
}

extern "C" void kernel_launch(void* const* d_in, const int* in_sizes, int n_in,
                              void* d_out, int out_size, void* d_ws, size_t ws_size,
                              hipStream_t stream)
{
    const float* x     = (const float*)d_in[0];
    const float* Wq    = (const float*)d_in[1];
    const float* bq    = (const float*)d_in[2];
    const float* Wk    = (const float*)d_in[3];
    const float* bk    = (const float*)d_in[4];
    const float* Wv    = (const float*)d_in[5];
    const float* bv    = (const float*)d_in[6];
    const float* Wo    = (const float*)d_in[7];
    const float* bo    = (const float*)d_in[8];
    const float* gamma = (const float*)d_in[9];
    const float* beta  = (const float*)d_in[10];
    float* out = (float*)d_out;

    char* ws = (char*)d_ws;
    bf16* xb  = (bf16*)(ws + (size_t)0);
    bf16* Qb  = (bf16*)(ws + (size_t)33554432);   // also AO
    bf16* Kb  = (bf16*)(ws + (size_t)67108864);
    bf16* VT  = (bf16*)(ws + (size_t)100663296);
    bf16* Sb  = (bf16*)(ws + (size_t)134217728);  // also fp32 preLN
    bf16* Wqb = (bf16*)(ws + (size_t)201326592);
    bf16* Wkb = Wqb + 1048576;
    bf16* Wvb = Wkb + 1048576;
    bf16* Wob = Wvb + 1048576;

    // 1) casts
    cast_f32_bf16<<<16384, 256, 0, stream>>>(x, xb, 16777216);
    cast_f32_bf16<<<1024, 256, 0, stream>>>(Wq, Wqb, 1048576);
    cast_f32_bf16<<<1024, 256, 0, stream>>>(Wk, Wkb, 1048576);
    cast_f32_bf16<<<1024, 256, 0, stream>>>(Wv, Wvb, 1048576);
    cast_f32_bf16<<<1024, 256, 0, stream>>>(Wo, Wob, 1048576);

    // 2) Q = xb@Wq^T + bq   [16384,1024]
    gemm_bt<<<dim3(8, 128, 1), 256, 0, stream>>>(
        xb, 1024, 0, Wqb, 1024, 0, (void*)Qb, 1024, 0, bq, 1, 1.0f, 0, 1024);
    // 3) K
    gemm_bt<<<dim3(8, 128, 1), 256, 0, stream>>>(
        xb, 1024, 0, Wkb, 1024, 0, (void*)Kb, 1024, 0, bk, 1, 1.0f, 0, 1024);
    // 4) VT = Wv@xb^T + bv(row)   [1024,16384]
    gemm_bt<<<dim3(128, 8, 1), 256, 0, stream>>>(
        Wvb, 1024, 0, xb, 1024, 0, (void*)VT, 16384, 0, bv, 2, 1.0f, 0, 1024);
    // 5) scores = Q@K^T / 32   per batch, bf16 [2048,2048]
    gemm_bt<<<dim3(16, 16, 8), 256, 0, stream>>>(
        Qb, 1024, 2097152, Kb, 1024, 2097152, (void*)Sb, 2048, 4194304,
        nullptr, 0, 0.03125f, 0, 1024);
    // 6) softmax in place
    softmax2048<<<16384, 256, 0, stream>>>(Sb);
    // 7) AO = P@VT^T  (per batch; VT batch slice = columns b*2048..; into Qb)
    gemm_bt<<<dim3(8, 16, 8), 256, 0, stream>>>(
        Sb, 2048, 4194304, VT, 16384, 2048, (void*)Qb, 1024, 2097152,
        nullptr, 0, 1.0f, 0, 2048);
    // 8) preLN = AO@Wo^T + bo  (fp32, into Sb region)
    gemm_bt<<<dim3(8, 128, 1), 256, 0, stream>>>(
        Qb, 1024, 0, Wob, 1024, 0, (void*)Sb, 1024, 0, bo, 1, 1.0f, 1, 1024);
    // 9) LayerNorm(pre + x)
    ln_res<<<16384, 256, 0, stream>>>((const float*)Sb, x, gamma, beta, out);
}

// Round 2
// 671.804 us; speedup vs baseline: 1.0994x; 1.0994x over previous
//
#include <hip/hip_runtime.h>
#include <hip/hip_bf16.h>
#include <math.h>

// SelfAttentionLayer: B=8,S=2048,D=1024 (fp32 interface, bf16 MFMA internals).
// R2 changes vs R1:
//  - XCD chunk swizzle in gemm_bt: contiguous flat-block range per XCD (flat%8
//    is the dispatch round-robin) -> A/B tile reuse lands in one XCD's L2.
//  - LDS chunk-rotation swizzle: chunk pos (row>>1)&3-rotated. Staging rotates
//    the GLOBAL source per lane (global_load_lds LDS dst must stay lane*16);
//    fragment reads un-rotate. Kills the 8-way ds_read_b128 bank conflict
//    (8 even lanes on one 4-bank group) down to free 2-way.
//  - preLN stored bf16 (was fp32): -48MB traffic, smaller L3 footprint.

typedef __bf16 bf16;
typedef __attribute__((ext_vector_type(8))) __bf16 bf16x8;
typedef __attribute__((ext_vector_type(4))) __bf16 bf16x4;
typedef __attribute__((ext_vector_type(4))) float f32x4;

__device__ __forceinline__ void async16(const bf16* g, bf16* l) {
    __builtin_amdgcn_global_load_lds(
        (const __attribute__((address_space(1))) void*)g,
        (__attribute__((address_space(3))) void*)l, 16, 0, 0);
}

__global__ __launch_bounds__(256) void cast_f32_bf16(
    const float* __restrict__ in, bf16* __restrict__ out, int n)
{
    int i = (blockIdx.x * 256 + threadIdx.x) * 4;
    if (i >= n) return;
    float4 v = *(const float4*)(in + i);
    bf16x4 o = { (bf16)v.x, (bf16)v.y, (bf16)v.z, (bf16)v.w };
    *(bf16x4*)(out + i) = o;
}

// C[m,n] = scale * sum_k A[m,k]*B[n,k] + bias;  A:[M,K] lda, B:[N,K] ldb (bf16).
// bias_mode: 0 none, 1 bias[n], 2 bias[m]. c_fp32: store fp32 else bf16.
// grid: (N/128, M/128, batches); 256 threads = 4 waves, each wave 64x64 quadrant.
__global__ __launch_bounds__(256) void gemm_bt(
    const bf16* __restrict__ A, long lda, long sA,
    const bf16* __restrict__ B, long ldb, long sB,
    void* __restrict__ Cv, long ldc, long sC,
    const float* __restrict__ bias, int bias_mode,
    float scale, int c_fp32, int K)
{
    __shared__ bf16 lA[128 * 32];   // 8 KB, [m][k-chunk-rotated]
    __shared__ bf16 lB[128 * 32];

    // ---- XCD chunk swizzle: dispatch is x-fastest flat, flat%8 -> XCD.
    // Remap so each XCD owns a contiguous flat range (n-fastest inside).
    const int gx = gridDim.x, gy = gridDim.y;
    const int slice = gx * gy;
    const int total = slice * gridDim.z;
    int flat = ((int)blockIdx.z * gy + (int)blockIdx.y) * gx + (int)blockIdx.x;
    if ((total & 7) == 0)
        flat = (flat & 7) * (total >> 3) + (flat >> 3);
    const int bz = flat / slice;
    const int rem = flat - bz * slice;
    const int by = rem / gx;
    const int bx = rem - by * gx;

    const int tid = threadIdx.x;
    const long tM = (long)by * 128;
    const long tN = (long)bx * 128;
    A += (long)bz * sA;
    B += (long)bz * sB;

    // staging: thread -> (row = tid/4, LDS chunk pos = tid%4); LDS byte offset
    // = tid*16 (lane-contiguous, required by global_load_lds). The GLOBAL
    // chunk this lane fetches is rotated: c = (pos - (row>>1)) & 3.
    // (row+64 has the same (row>>1)&3 since 32 % 4 == 0.)
    const int ra = tid >> 2;
    const int posc = tid & 3;
    const int ca = (((posc - (ra >> 1)) & 3)) * 8;   // global chunk offset, bf16 elems
    const bf16* ga0 = A + (tM + ra) * lda + ca;
    const bf16* ga1 = ga0 + 64 * lda;
    const bf16* gb0 = B + (tN + ra) * ldb + ca;
    const bf16* gb1 = gb0 + 64 * ldb;
    bf16* la0 = lA + ra * 32 + posc * 8;
    bf16* la1 = la0 + 64 * 32;
    bf16* lb0 = lB + ra * 32 + posc * 8;
    bf16* lb1 = lb0 + 64 * 32;

    const int w = tid >> 6, lane = tid & 63;
    const int wm = (w & 1) * 64, wn = (w >> 1) * 64;
    const int quad = lane >> 4, lr = lane & 15;

    f32x4 acc[4][4] = {};

    for (int k0 = 0; k0 < K; k0 += 32) {
        async16(ga0 + k0, la0);
        async16(ga1 + k0, la1);
        async16(gb0 + k0, lb0);
        async16(gb1 + k0, lb1);
        __syncthreads();

        bf16x8 af[4], bfr[4];
#pragma unroll
        for (int i = 0; i < 4; i++) {
            const int rowA = wm + i * 16 + lr;
            af[i] = *(const bf16x8*)&lA[rowA * 32 + (((quad + (rowA >> 1)) & 3) << 3)];
        }
#pragma unroll
        for (int j = 0; j < 4; j++) {
            const int rowB = wn + j * 16 + lr;
            bfr[j] = *(const bf16x8*)&lB[rowB * 32 + (((quad + (rowB >> 1)) & 3) << 3)];
        }
#pragma unroll
        for (int i = 0; i < 4; i++)
#pragma unroll
            for (int j = 0; j < 4; j++)
                acc[i][j] = __builtin_amdgcn_mfma_f32_16x16x32_bf16(
                    af[i], bfr[j], acc[i][j], 0, 0, 0);
        __syncthreads();
    }

    // epilogue: C/D layout col=lane&15, row=(lane>>4)*4+reg  [verified m89/m91]
    if (c_fp32) {
        float* C = (float*)Cv + (long)bz * sC;
#pragma unroll
        for (int i = 0; i < 4; i++) {
#pragma unroll
            for (int r = 0; r < 4; r++) {
                const long gm = tM + wm + i * 16 + quad * 4 + r;
                const float bm = (bias_mode == 2) ? bias[gm] : 0.0f;
                float* crow = C + gm * ldc + tN + wn;
#pragma unroll
                for (int j = 0; j < 4; j++) {
                    float v = acc[i][j][r] * scale + bm;
                    if (bias_mode == 1) v += bias[tN + wn + j * 16 + lr];
                    crow[j * 16 + lr] = v;
                }
            }
        }
    } else {
        bf16* C = (bf16*)Cv + (long)bz * sC;
#pragma unroll
        for (int i = 0; i < 4; i++) {
#pragma unroll
            for (int r = 0; r < 4; r++) {
                const long gm = tM + wm + i * 16 + quad * 4 + r;
                const float bm = (bias_mode == 2) ? bias[gm] : 0.0f;
                bf16* crow = C + gm * ldc + tN + wn;
#pragma unroll
                for (int j = 0; j < 4; j++) {
                    float v = acc[i][j][r] * scale + bm;
                    if (bias_mode == 1) v += bias[tN + wn + j * 16 + lr];
                    crow[j * 16 + lr] = (bf16)v;
                }
            }
        }
    }
}

// in-place softmax over rows of 2048 bf16; one block (4 waves) per row
__global__ __launch_bounds__(256) void softmax2048(bf16* __restrict__ S)
{
    const long row = blockIdx.x;
    bf16* p = S + row * 2048;
    const int t = threadIdx.x;

    bf16x8 v = *(const bf16x8*)(p + t * 8);
    float f[8];
    float m = -3.0e38f;
#pragma unroll
    for (int i = 0; i < 8; i++) { f[i] = (float)v[i]; m = fmaxf(m, f[i]); }
    for (int o = 32; o; o >>= 1) m = fmaxf(m, __shfl_down(m, o));

    __shared__ float sm[4], ssum[4];
    if ((t & 63) == 0) sm[t >> 6] = m;
    __syncthreads();
    m = fmaxf(fmaxf(sm[0], sm[1]), fmaxf(sm[2], sm[3]));

    float s = 0.0f;
#pragma unroll
    for (int i = 0; i < 8; i++) { f[i] = __expf(f[i] - m); s += f[i]; }
    for (int o = 32; o; o >>= 1) s += __shfl_down(s, o);
    if ((t & 63) == 0) ssum[t >> 6] = s;
    __syncthreads();
    s = ssum[0] + ssum[1] + ssum[2] + ssum[3];

    const float inv = 1.0f / s;
    bf16x8 ov;
#pragma unroll
    for (int i = 0; i < 8; i++) ov[i] = (bf16)(f[i] * inv);
    *(bf16x8*)(p + t * 8) = ov;
}

// out = LN(pre + x) * gamma + beta; pre bf16, x fp32; rows of 1024
__global__ __launch_bounds__(256) void ln_res(
    const bf16* __restrict__ pre, const float* __restrict__ x,
    const float* __restrict__ gamma, const float* __restrict__ beta,
    float* __restrict__ out)
{
    const long row = blockIdx.x;
    const int t = threadIdx.x;
    const long base = row * 1024 + t * 4;

    bf16x4 a = *(const bf16x4*)(pre + base);
    float4 b = *(const float4*)(x + base);
    float v0 = (float)a[0] + b.x, v1 = (float)a[1] + b.y;
    float v2 = (float)a[2] + b.z, v3 = (float)a[3] + b.w;

    float s = v0 + v1 + v2 + v3;
    float q = v0 * v0 + v1 * v1 + v2 * v2 + v3 * v3;
    for (int o = 32; o; o >>= 1) { s += __shfl_down(s, o); q += __shfl_down(q, o); }

    __shared__ float ls[4], lq[4];
    if ((t & 63) == 0) { ls[t >> 6] = s; lq[t >> 6] = q; }
    __syncthreads();
    s = ls[0] + ls[1] + ls[2] + ls[3];
    q = lq[0] + lq[1] + lq[2] + lq[3];

    const float mean = s * (1.0f / 1024.0f);
    const float var = q * (1.0f / 1024.0f) - mean * mean;
    const float rstd = rsqrtf(var + 1e-5f);

    const int c = t * 4;
    float4 g = *(const float4*)(gamma + c);
    float4 be = *(const float4*)(beta + c);
    float4 o;
    o.x = (v0 - mean) * rstd * g.x + be.x;
    o.y = (v1 - mean) * rstd * g.y + be.y;
    o.z = (v2 - mean) * rstd * g.z + be.z;
    o.w = (v3 - mean) * rstd * g.w + be.w;
    *(float4*)(out + base) = o;
}

extern "C" void kernel_launch(void* const* d_in, const int* in_sizes, int n_in,
                              void* d_out, int out_size, void* d_ws, size_t ws_size,
                              hipStream_t stream)
{
    const float* x     = (const float*)d_in[0];
    const float* Wq    = (const float*)d_in[1];
    const float* bq    = (const float*)d_in[2];
    const float* Wk    = (const float*)d_in[3];
    const float* bk    = (const float*)d_in[4];
    const float* Wv    = (const float*)d_in[5];
    const float* bv    = (const float*)d_in[6];
    const float* Wo    = (const float*)d_in[7];
    const float* bo    = (const float*)d_in[8];
    const float* gamma = (const float*)d_in[9];
    const float* beta  = (const float*)d_in[10];
    float* out = (float*)d_out;

    char* ws = (char*)d_ws;
    bf16* xb  = (bf16*)(ws + (size_t)0);
    bf16* Qb  = (bf16*)(ws + (size_t)33554432);   // also AO
    bf16* Kb  = (bf16*)(ws + (size_t)67108864);
    bf16* VT  = (bf16*)(ws + (size_t)100663296);
    bf16* Sb  = (bf16*)(ws + (size_t)134217728);  // also bf16 preLN
    bf16* Wqb = (bf16*)(ws + (size_t)201326592);
    bf16* Wkb = Wqb + 1048576;
    bf16* Wvb = Wkb + 1048576;
    bf16* Wob = Wvb + 1048576;

    // 1) casts
    cast_f32_bf16<<<16384, 256, 0, stream>>>(x, xb, 16777216);
    cast_f32_bf16<<<1024, 256, 0, stream>>>(Wq, Wqb, 1048576);
    cast_f32_bf16<<<1024, 256, 0, stream>>>(Wk, Wkb, 1048576);
    cast_f32_bf16<<<1024, 256, 0, stream>>>(Wv, Wvb, 1048576);
    cast_f32_bf16<<<1024, 256, 0, stream>>>(Wo, Wob, 1048576);

    // 2) Q = xb@Wq^T + bq   [16384,1024]
    gemm_bt<<<dim3(8, 128, 1), 256, 0, stream>>>(
        xb, 1024, 0, Wqb, 1024, 0, (void*)Qb, 1024, 0, bq, 1, 1.0f, 0, 1024);
    // 3) K
    gemm_bt<<<dim3(8, 128, 1), 256, 0, stream>>>(
        xb, 1024, 0, Wkb, 1024, 0, (void*)Kb, 1024, 0, bk, 1, 1.0f, 0, 1024);
    // 4) VT = Wv@xb^T + bv(row)   [1024,16384]
    gemm_bt<<<dim3(128, 8, 1), 256, 0, stream>>>(
        Wvb, 1024, 0, xb, 1024, 0, (void*)VT, 16384, 0, bv, 2, 1.0f, 0, 1024);
    // 5) scores = Q@K^T / 32   per batch, bf16 [2048,2048]
    gemm_bt<<<dim3(16, 16, 8), 256, 0, stream>>>(
        Qb, 1024, 2097152, Kb, 1024, 2097152, (void*)Sb, 2048, 4194304,
        nullptr, 0, 0.03125f, 0, 1024);
    // 6) softmax in place
    softmax2048<<<16384, 256, 0, stream>>>(Sb);
    // 7) AO = P@VT^T  (per batch; VT batch slice = columns b*2048..; into Qb)
    gemm_bt<<<dim3(8, 16, 8), 256, 0, stream>>>(
        Sb, 2048, 4194304, VT, 16384, 2048, (void*)Qb, 1024, 2097152,
        nullptr, 0, 1.0f, 0, 2048);
    // 8) preLN = AO@Wo^T + bo  (bf16, into Sb region)
    gemm_bt<<<dim3(8, 128, 1), 256, 0, stream>>>(
        Qb, 1024, 0, Wob, 1024, 0, (void*)Sb, 1024, 0, bo, 1, 1.0f, 0, 1024);
    // 9) LayerNorm(pre + x)
    ln_res<<<16384, 256, 0, stream>>>((const bf16*)Sb, x, gamma, beta, out);
}

// Round 3
// 622.859 us; speedup vs baseline: 1.1858x; 1.0786x over previous
//
#include <hip/hip_runtime.h>
#include <hip/hip_bf16.h>
#include <math.h>

// SelfAttentionLayer: B=8,S=2048,D=1024 (fp32 interface, bf16 MFMA internals).
// R3 change vs R2: double-buffered LDS staging with ONE barrier per K-iter.
//   Per iter: issue async global_load_lds for iter+1 into buf[nxt], THEN
//   ds_read+MFMA from buf[cur], THEN __syncthreads. The barrier's implicit
//   vmcnt(0) drain now happens a full compute-phase (~500-700cy) after load
//   issue instead of immediately -> staging latency overlapped with own
//   compute (R2 counters showed ~47% stall: MFMA 21% + VALU 32%, HBM 10%,
//   conflicts 0 -> latency-bound, not BW/conflict-bound).
// Kept from R2: XCD chunk swizzle (FETCH 278->68MB), LDS chunk-rotation
//   swizzle (bank conflicts 8.4M->0), bf16 preLN.

typedef __bf16 bf16;
typedef __attribute__((ext_vector_type(8))) __bf16 bf16x8;
typedef __attribute__((ext_vector_type(4))) __bf16 bf16x4;
typedef __attribute__((ext_vector_type(4))) float f32x4;

__device__ __forceinline__ void async16(const bf16* g, bf16* l) {
    __builtin_amdgcn_global_load_lds(
        (const __attribute__((address_space(1))) void*)g,
        (__attribute__((address_space(3))) void*)l, 16, 0, 0);
}

__global__ __launch_bounds__(256) void cast_f32_bf16(
    const float* __restrict__ in, bf16* __restrict__ out, int n)
{
    int i = (blockIdx.x * 256 + threadIdx.x) * 4;
    if (i >= n) return;
    float4 v = *(const float4*)(in + i);
    bf16x4 o = { (bf16)v.x, (bf16)v.y, (bf16)v.z, (bf16)v.w };
    *(bf16x4*)(out + i) = o;
}

// C[m,n] = scale * sum_k A[m,k]*B[n,k] + bias;  A:[M,K] lda, B:[N,K] ldb (bf16).
// bias_mode: 0 none, 1 bias[n], 2 bias[m]. c_fp32: store fp32 else bf16.
// grid: (N/128, M/128, batches); 256 threads = 4 waves, each wave 64x64 quadrant.
__global__ __launch_bounds__(256) void gemm_bt(
    const bf16* __restrict__ A, long lda, long sA,
    const bf16* __restrict__ B, long ldb, long sB,
    void* __restrict__ Cv, long ldc, long sC,
    const float* __restrict__ bias, int bias_mode,
    float scale, int c_fp32, int K)
{
    __shared__ bf16 lds[2][2 * 128 * 32];   // [buf][A tile 4K elems | B tile 4K elems]

    // ---- XCD chunk swizzle: dispatch is x-fastest flat, flat%8 -> XCD.
    const int gx = gridDim.x, gy = gridDim.y;
    const int slice = gx * gy;
    const int total = slice * gridDim.z;
    int flat = ((int)blockIdx.z * gy + (int)blockIdx.y) * gx + (int)blockIdx.x;
    if ((total & 7) == 0)
        flat = (flat & 7) * (total >> 3) + (flat >> 3);
    const int bz = flat / slice;
    const int rem = flat - bz * slice;
    const int by = rem / gx;
    const int bx = rem - by * gx;

    const int tid = threadIdx.x;
    const long tM = (long)by * 128;
    const long tN = (long)bx * 128;
    A += (long)bz * sA;
    B += (long)bz * sB;

    // staging: thread -> (row = tid/4, LDS chunk pos = tid%4); LDS offset
    // lane-contiguous (required by global_load_lds); GLOBAL chunk rotated by
    // (row>>1)&3 to kill ds_read_b128 bank conflicts (un-rotated on read).
    const int ra = tid >> 2;
    const int posc = tid & 3;
    const int ca = (((posc - (ra >> 1)) & 3)) * 8;
    const bf16* ga0 = A + (tM + ra) * lda + ca;
    const bf16* ga1 = ga0 + 64 * lda;
    const bf16* gb0 = B + (tN + ra) * ldb + ca;
    const bf16* gb1 = gb0 + 64 * ldb;
    const int loA = ra * 32 + posc * 8;          // within A half
    const int loB = 4096 + ra * 32 + posc * 8;   // B half starts at elem 4096

    const int w = tid >> 6, lane = tid & 63;
    const int wm = (w & 1) * 64, wn = (w >> 1) * 64;
    const int quad = lane >> 4, lr = lane & 15;

    f32x4 acc[4][4] = {};

    // prologue: stage k=0 into buf0
    {
        bf16* p = lds[0];
        async16(ga0, p + loA);
        async16(ga1, p + loA + 64 * 32);
        async16(gb0, p + loB);
        async16(gb1, p + loB + 64 * 32);
    }
    __syncthreads();

    for (int k0 = 0; k0 < K; k0 += 32) {
        const int cur = (k0 >> 5) & 1;
        bf16* curb = lds[cur];

        // prefetch next tile into the other buffer (drained at the barrier
        // below -> a full compute-phase of in-flight time)
        if (k0 + 32 < K) {
            bf16* nxtb = lds[cur ^ 1];
            async16(ga0 + k0 + 32, nxtb + loA);
            async16(ga1 + k0 + 32, nxtb + loA + 64 * 32);
            async16(gb0 + k0 + 32, nxtb + loB);
            async16(gb1 + k0 + 32, nxtb + loB + 64 * 32);
        }

        bf16x8 af[4], bfr[4];
#pragma unroll
        for (int i = 0; i < 4; i++) {
            const int rowA = wm + i * 16 + lr;
            af[i] = *(const bf16x8*)&curb[rowA * 32 + (((quad + (rowA >> 1)) & 3) << 3)];
        }
#pragma unroll
        for (int j = 0; j < 4; j++) {
            const int rowB = wn + j * 16 + lr;
            bfr[j] = *(const bf16x8*)&curb[4096 + rowB * 32 + (((quad + (rowB >> 1)) & 3) << 3)];
        }
#pragma unroll
        for (int i = 0; i < 4; i++)
#pragma unroll
            for (int j = 0; j < 4; j++)
                acc[i][j] = __builtin_amdgcn_mfma_f32_16x16x32_bf16(
                    af[i], bfr[j], acc[i][j], 0, 0, 0);

        __syncthreads();   // drains prefetch vmcnt + protects buf[cur^1] reuse
    }

    // epilogue: C/D layout col=lane&15, row=(lane>>4)*4+reg  [verified m89/m91]
    if (c_fp32) {
        float* C = (float*)Cv + (long)bz * sC;
#pragma unroll
        for (int i = 0; i < 4; i++) {
#pragma unroll
            for (int r = 0; r < 4; r++) {
                const long gm = tM + wm + i * 16 + quad * 4 + r;
                const float bm = (bias_mode == 2) ? bias[gm] : 0.0f;
                float* crow = C + gm * ldc + tN + wn;
#pragma unroll
                for (int j = 0; j < 4; j++) {
                    float v = acc[i][j][r] * scale + bm;
                    if (bias_mode == 1) v += bias[tN + wn + j * 16 + lr];
                    crow[j * 16 + lr] = v;
                }
            }
        }
    } else {
        bf16* C = (bf16*)Cv + (long)bz * sC;
#pragma unroll
        for (int i = 0; i < 4; i++) {
#pragma unroll
            for (int r = 0; r < 4; r++) {
                const long gm = tM + wm + i * 16 + quad * 4 + r;
                const float bm = (bias_mode == 2) ? bias[gm] : 0.0f;
                bf16* crow = C + gm * ldc + tN + wn;
#pragma unroll
                for (int j = 0; j < 4; j++) {
                    float v = acc[i][j][r] * scale + bm;
                    if (bias_mode == 1) v += bias[tN + wn + j * 16 + lr];
                    crow[j * 16 + lr] = (bf16)v;
                }
            }
        }
    }
}

// in-place softmax over rows of 2048 bf16; one block (4 waves) per row
__global__ __launch_bounds__(256) void softmax2048(bf16* __restrict__ S)
{
    const long row = blockIdx.x;
    bf16* p = S + row * 2048;
    const int t = threadIdx.x;

    bf16x8 v = *(const bf16x8*)(p + t * 8);
    float f[8];
    float m = -3.0e38f;
#pragma unroll
    for (int i = 0; i < 8; i++) { f[i] = (float)v[i]; m = fmaxf(m, f[i]); }
    for (int o = 32; o; o >>= 1) m = fmaxf(m, __shfl_down(m, o));

    __shared__ float sm[4], ssum[4];
    if ((t & 63) == 0) sm[t >> 6] = m;
    __syncthreads();
    m = fmaxf(fmaxf(sm[0], sm[1]), fmaxf(sm[2], sm[3]));

    float s = 0.0f;
#pragma unroll
    for (int i = 0; i < 8; i++) { f[i] = __expf(f[i] - m); s += f[i]; }
    for (int o = 32; o; o >>= 1) s += __shfl_down(s, o);
    if ((t & 63) == 0) ssum[t >> 6] = s;
    __syncthreads();
    s = ssum[0] + ssum[1] + ssum[2] + ssum[3];

    const float inv = 1.0f / s;
    bf16x8 ov;
#pragma unroll
    for (int i = 0; i < 8; i++) ov[i] = (bf16)(f[i] * inv);
    *(bf16x8*)(p + t * 8) = ov;
}

// out = LN(pre + x) * gamma + beta; pre bf16, x fp32; rows of 1024
__global__ __launch_bounds__(256) void ln_res(
    const bf16* __restrict__ pre, const float* __restrict__ x,
    const float* __restrict__ gamma, const float* __restrict__ beta,
    float* __restrict__ out)
{
    const long row = blockIdx.x;
    const int t = threadIdx.x;
    const long base = row * 1024 + t * 4;

    bf16x4 a = *(const bf16x4*)(pre + base);
    float4 b = *(const float4*)(x + base);
    float v0 = (float)a[0] + b.x, v1 = (float)a[1] + b.y;
    float v2 = (float)a[2] + b.z, v3 = (float)a[3] + b.w;

    float s = v0 + v1 + v2 + v3;
    float q = v0 * v0 + v1 * v1 + v2 * v2 + v3 * v3;
    for (int o = 32; o; o >>= 1) { s += __shfl_down(s, o); q += __shfl_down(q, o); }

    __shared__ float ls[4], lq[4];
    if ((t & 63) == 0) { ls[t >> 6] = s; lq[t >> 6] = q; }
    __syncthreads();
    s = ls[0] + ls[1] + ls[2] + ls[3];
    q = lq[0] + lq[1] + lq[2] + lq[3];

    const float mean = s * (1.0f / 1024.0f);
    const float var = q * (1.0f / 1024.0f) - mean * mean;
    const float rstd = rsqrtf(var + 1e-5f);

    const int c = t * 4;
    float4 g = *(const float4*)(gamma + c);
    float4 be = *(const float4*)(beta + c);
    float4 o;
    o.x = (v0 - mean) * rstd * g.x + be.x;
    o.y = (v1 - mean) * rstd * g.y + be.y;
    o.z = (v2 - mean) * rstd * g.z + be.z;
    o.w = (v3 - mean) * rstd * g.w + be.w;
    *(float4*)(out + base) = o;
}

extern "C" void kernel_launch(void* const* d_in, const int* in_sizes, int n_in,
                              void* d_out, int out_size, void* d_ws, size_t ws_size,
                              hipStream_t stream)
{
    const float* x     = (const float*)d_in[0];
    const float* Wq    = (const float*)d_in[1];
    const float* bq    = (const float*)d_in[2];
    const float* Wk    = (const float*)d_in[3];
    const float* bk    = (const float*)d_in[4];
    const float* Wv    = (const float*)d_in[5];
    const float* bv    = (const float*)d_in[6];
    const float* Wo    = (const float*)d_in[7];
    const float* bo    = (const float*)d_in[8];
    const float* gamma = (const float*)d_in[9];
    const float* beta  = (const float*)d_in[10];
    float* out = (float*)d_out;

    char* ws = (char*)d_ws;
    bf16* xb  = (bf16*)(ws + (size_t)0);
    bf16* Qb  = (bf16*)(ws + (size_t)33554432);   // also AO
    bf16* Kb  = (bf16*)(ws + (size_t)67108864);
    bf16* VT  = (bf16*)(ws + (size_t)100663296);
    bf16* Sb  = (bf16*)(ws + (size_t)134217728);  // also bf16 preLN
    bf16* Wqb = (bf16*)(ws + (size_t)201326592);
    bf16* Wkb = Wqb + 1048576;
    bf16* Wvb = Wkb + 1048576;
    bf16* Wob = Wvb + 1048576;

    // 1) casts
    cast_f32_bf16<<<16384, 256, 0, stream>>>(x, xb, 16777216);
    cast_f32_bf16<<<1024, 256, 0, stream>>>(Wq, Wqb, 1048576);
    cast_f32_bf16<<<1024, 256, 0, stream>>>(Wk, Wkb, 1048576);
    cast_f32_bf16<<<1024, 256, 0, stream>>>(Wv, Wvb, 1048576);
    cast_f32_bf16<<<1024, 256, 0, stream>>>(Wo, Wob, 1048576);

    // 2) Q = xb@Wq^T + bq   [16384,1024]
    gemm_bt<<<dim3(8, 128, 1), 256, 0, stream>>>(
        xb, 1024, 0, Wqb, 1024, 0, (void*)Qb, 1024, 0, bq, 1, 1.0f, 0, 1024);
    // 3) K
    gemm_bt<<<dim3(8, 128, 1), 256, 0, stream>>>(
        xb, 1024, 0, Wkb, 1024, 0, (void*)Kb, 1024, 0, bk, 1, 1.0f, 0, 1024);
    // 4) VT = Wv@xb^T + bv(row)   [1024,16384]
    gemm_bt<<<dim3(128, 8, 1), 256, 0, stream>>>(
        Wvb, 1024, 0, xb, 1024, 0, (void*)VT, 16384, 0, bv, 2, 1.0f, 0, 1024);
    // 5) scores = Q@K^T / 32   per batch, bf16 [2048,2048]
    gemm_bt<<<dim3(16, 16, 8), 256, 0, stream>>>(
        Qb, 1024, 2097152, Kb, 1024, 2097152, (void*)Sb, 2048, 4194304,
        nullptr, 0, 0.03125f, 0, 1024);
    // 6) softmax in place
    softmax2048<<<16384, 256, 0, stream>>>(Sb);
    // 7) AO = P@VT^T  (per batch; VT batch slice = columns b*2048..; into Qb)
    gemm_bt<<<dim3(8, 16, 8), 256, 0, stream>>>(
        Sb, 2048, 4194304, VT, 16384, 2048, (void*)Qb, 1024, 2097152,
        nullptr, 0, 1.0f, 0, 2048);
    // 8) preLN = AO@Wo^T + bo  (bf16, into Sb region)
    gemm_bt<<<dim3(8, 128, 1), 256, 0, stream>>>(
        Qb, 1024, 0, Wob, 1024, 0, (void*)Sb, 1024, 0, bo, 1, 1.0f, 0, 1024);
    // 9) LayerNorm(pre + x)
    ln_res<<<16384, 256, 0, stream>>>((const bf16*)Sb, x, gamma, beta, out);
}

// Round 4
// 579.986 us; speedup vs baseline: 1.2735x; 1.0739x over previous
//
#include <hip/hip_runtime.h>
#include <hip/hip_bf16.h>
#include <math.h>

// SelfAttentionLayer: B=8,S=2048,D=1024 (fp32 interface, bf16 MFMA internals).
// R4 change vs R3: triple-buffered K-loop with fine-grained vmcnt + RAW
//   s_barrier (no __syncthreads in the loop). Per iter: s_waitcnt vmcnt(4)
//   waits only for the batch issued TWO iters ago (~1800cy in flight, covers
//   HBM-miss 900cy), raw barrier (no compiler vmcnt(0) drain!), then issue
//   batch i+2, then ds_read+MFMA. R3's 919cy/block-iter had ~500cy exposed
//   latency because __syncthreads drained the same-iter prefetch (vmcnt(0)).
// Kept: XCD chunk swizzle, LDS chunk-rotation swizzle (0 conflicts), bf16
//   preLN, dbuf->now tbuf.

typedef __bf16 bf16;
typedef __attribute__((ext_vector_type(8))) __bf16 bf16x8;
typedef __attribute__((ext_vector_type(4))) __bf16 bf16x4;
typedef __attribute__((ext_vector_type(4))) float f32x4;

__device__ __forceinline__ void async16(const bf16* g, bf16* l) {
    __builtin_amdgcn_global_load_lds(
        (const __attribute__((address_space(1))) void*)g,
        (__attribute__((address_space(3))) void*)l, 16, 0, 0);
}

// s_waitcnt imm: bits[3:0] vmcnt, [6:4] expcnt, [11:8] lgkmcnt
#define WAITCNT_VM(n) __builtin_amdgcn_s_waitcnt((15 << 8) | (7 << 4) | (n))

__global__ __launch_bounds__(256) void cast_f32_bf16(
    const float* __restrict__ in, bf16* __restrict__ out, int n)
{
    int i = (blockIdx.x * 256 + threadIdx.x) * 4;
    if (i >= n) return;
    float4 v = *(const float4*)(in + i);
    bf16x4 o = { (bf16)v.x, (bf16)v.y, (bf16)v.z, (bf16)v.w };
    *(bf16x4*)(out + i) = o;
}

// C[m,n] = scale * sum_k A[m,k]*B[n,k] + bias;  A:[M,K] lda, B:[N,K] ldb (bf16).
// bias_mode: 0 none, 1 bias[n], 2 bias[m]. c_fp32: store fp32 else bf16.
// grid: (N/128, M/128, batches); 256 threads = 4 waves, each wave 64x64 quadrant.
__global__ __launch_bounds__(256) void gemm_bt(
    const bf16* __restrict__ A, long lda, long sA,
    const bf16* __restrict__ B, long ldb, long sB,
    void* __restrict__ Cv, long ldc, long sC,
    const float* __restrict__ bias, int bias_mode,
    float scale, int c_fp32, int K)
{
    __shared__ bf16 lds[3][2 * 128 * 32];   // 3 stages x (A 4096 | B 4096) = 48 KB

    // ---- XCD chunk swizzle: dispatch is x-fastest flat, flat%8 -> XCD.
    const int gx = gridDim.x, gy = gridDim.y;
    const int slice = gx * gy;
    const int total = slice * gridDim.z;
    int flat = ((int)blockIdx.z * gy + (int)blockIdx.y) * gx + (int)blockIdx.x;
    if ((total & 7) == 0)
        flat = (flat & 7) * (total >> 3) + (flat >> 3);
    const int bz = flat / slice;
    const int rem = flat - bz * slice;
    const int by = rem / gx;
    const int bx = rem - by * gx;

    const int tid = threadIdx.x;
    const long tM = (long)by * 128;
    const long tN = (long)bx * 128;
    A += (long)bz * sA;
    B += (long)bz * sB;

    // staging: thread -> (row = tid/4, LDS chunk pos = tid%4); LDS offset
    // lane-contiguous (global_load_lds requirement); GLOBAL chunk rotated by
    // (row>>1)&3 (un-rotated on read) -> 0 bank conflicts (R2-verified).
    const int ra = tid >> 2;
    const int posc = tid & 3;
    const int ca = (((posc - (ra >> 1)) & 3)) * 8;
    const bf16* ga0 = A + (tM + ra) * lda + ca;
    const bf16* ga1 = ga0 + 64 * lda;
    const bf16* gb0 = B + (tN + ra) * ldb + ca;
    const bf16* gb1 = gb0 + 64 * ldb;
    const int loA = ra * 32 + posc * 8;
    const int loB = 4096 + ra * 32 + posc * 8;

    const int w = tid >> 6, lane = tid & 63;
    const int wm = (w & 1) * 64, wn = (w >> 1) * 64;
    const int quad = lane >> 4, lr = lane & 15;

    f32x4 acc[4][4] = {};

    const int iters = K >> 5;

    // prologue: issue batches 0 and 1 (4 loads each -> vmcnt 8 outstanding)
    {
        bf16* p0 = lds[0];
        async16(ga0, p0 + loA);
        async16(ga1, p0 + loA + 64 * 32);
        async16(gb0, p0 + loB);
        async16(gb1, p0 + loB + 64 * 32);
        bf16* p1 = lds[1];
        const int k1 = 32;
        async16(ga0 + k1, p1 + loA);
        async16(ga1 + k1, p1 + loA + 64 * 32);
        async16(gb0 + k1, p1 + loB);
        async16(gb1 + k1, p1 + loB + 64 * 32);
    }

    int cur = 0;
    for (int it = 0; it < iters; ++it) {
        // wait own share of batch `it` landed: outstanding {it, it+1} = 8 -> 4
        if (it + 1 < iters) WAITCNT_VM(4);
        else WAITCNT_VM(0);
        __builtin_amdgcn_s_barrier();   // all waves' batch `it` landed; all
                                        // waves done reading buf[(it-1)%3]

        // issue batch it+2 into buf[(it+2)%3] == buf[(it-1)%3]
        if (it + 2 < iters) {
            int nb = cur + 2; if (nb >= 3) nb -= 3;
            bf16* p = lds[nb];
            const long ko = (long)(it + 2) << 5;
            async16(ga0 + ko, p + loA);
            async16(ga1 + ko, p + loA + 64 * 32);
            async16(gb0 + ko, p + loB);
            async16(gb1 + ko, p + loB + 64 * 32);
        }

        const bf16* curb = lds[cur];
        bf16x8 af[4], bfr[4];
#pragma unroll
        for (int i = 0; i < 4; i++) {
            const int rowA = wm + i * 16 + lr;
            af[i] = *(const bf16x8*)&curb[rowA * 32 + (((quad + (rowA >> 1)) & 3) << 3)];
        }
#pragma unroll
        for (int j = 0; j < 4; j++) {
            const int rowB = wn + j * 16 + lr;
            bfr[j] = *(const bf16x8*)&curb[4096 + rowB * 32 + (((quad + (rowB >> 1)) & 3) << 3)];
        }
#pragma unroll
        for (int i = 0; i < 4; i++)
#pragma unroll
            for (int j = 0; j < 4; j++)
                acc[i][j] = __builtin_amdgcn_mfma_f32_16x16x32_bf16(
                    af[i], bfr[j], acc[i][j], 0, 0, 0);

        if (++cur >= 3) cur = 0;
    }

    // epilogue: C/D layout col=lane&15, row=(lane>>4)*4+reg  [verified m89/m91]
    if (c_fp32) {
        float* C = (float*)Cv + (long)bz * sC;
#pragma unroll
        for (int i = 0; i < 4; i++) {
#pragma unroll
            for (int r = 0; r < 4; r++) {
                const long gm = tM + wm + i * 16 + quad * 4 + r;
                const float bm = (bias_mode == 2) ? bias[gm] : 0.0f;
                float* crow = C + gm * ldc + tN + wn;
#pragma unroll
                for (int j = 0; j < 4; j++) {
                    float v = acc[i][j][r] * scale + bm;
                    if (bias_mode == 1) v += bias[tN + wn + j * 16 + lr];
                    crow[j * 16 + lr] = v;
                }
            }
        }
    } else {
        bf16* C = (bf16*)Cv + (long)bz * sC;
#pragma unroll
        for (int i = 0; i < 4; i++) {
#pragma unroll
            for (int r = 0; r < 4; r++) {
                const long gm = tM + wm + i * 16 + quad * 4 + r;
                const float bm = (bias_mode == 2) ? bias[gm] : 0.0f;
                bf16* crow = C + gm * ldc + tN + wn;
#pragma unroll
                for (int j = 0; j < 4; j++) {
                    float v = acc[i][j][r] * scale + bm;
                    if (bias_mode == 1) v += bias[tN + wn + j * 16 + lr];
                    crow[j * 16 + lr] = (bf16)v;
                }
            }
        }
    }
}

// in-place softmax over rows of 2048 bf16; one block (4 waves) per row
__global__ __launch_bounds__(256) void softmax2048(bf16* __restrict__ S)
{
    const long row = blockIdx.x;
    bf16* p = S + row * 2048;
    const int t = threadIdx.x;

    bf16x8 v = *(const bf16x8*)(p + t * 8);
    float f[8];
    float m = -3.0e38f;
#pragma unroll
    for (int i = 0; i < 8; i++) { f[i] = (float)v[i]; m = fmaxf(m, f[i]); }
    for (int o = 32; o; o >>= 1) m = fmaxf(m, __shfl_down(m, o));

    __shared__ float sm[4], ssum[4];
    if ((t & 63) == 0) sm[t >> 6] = m;
    __syncthreads();
    m = fmaxf(fmaxf(sm[0], sm[1]), fmaxf(sm[2], sm[3]));

    float s = 0.0f;
#pragma unroll
    for (int i = 0; i < 8; i++) { f[i] = __expf(f[i] - m); s += f[i]; }
    for (int o = 32; o; o >>= 1) s += __shfl_down(s, o);
    if ((t & 63) == 0) ssum[t >> 6] = s;
    __syncthreads();
    s = ssum[0] + ssum[1] + ssum[2] + ssum[3];

    const float inv = 1.0f / s;
    bf16x8 ov;
#pragma unroll
    for (int i = 0; i < 8; i++) ov[i] = (bf16)(f[i] * inv);
    *(bf16x8*)(p + t * 8) = ov;
}

// out = LN(pre + x) * gamma + beta; pre bf16, x fp32; rows of 1024
__global__ __launch_bounds__(256) void ln_res(
    const bf16* __restrict__ pre, const float* __restrict__ x,
    const float* __restrict__ gamma, const float* __restrict__ beta,
    float* __restrict__ out)
{
    const long row = blockIdx.x;
    const int t = threadIdx.x;
    const long base = row * 1024 + t * 4;

    bf16x4 a = *(const bf16x4*)(pre + base);
    float4 b = *(const float4*)(x + base);
    float v0 = (float)a[0] + b.x, v1 = (float)a[1] + b.y;
    float v2 = (float)a[2] + b.z, v3 = (float)a[3] + b.w;

    float s = v0 + v1 + v2 + v3;
    float q = v0 * v0 + v1 * v1 + v2 * v2 + v3 * v3;
    for (int o = 32; o; o >>= 1) { s += __shfl_down(s, o); q += __shfl_down(q, o); }

    __shared__ float ls[4], lq[4];
    if ((t & 63) == 0) { ls[t >> 6] = s; lq[t >> 6] = q; }
    __syncthreads();
    s = ls[0] + ls[1] + ls[2] + ls[3];
    q = lq[0] + lq[1] + lq[2] + lq[3];

    const float mean = s * (1.0f / 1024.0f);
    const float var = q * (1.0f / 1024.0f) - mean * mean;
    const float rstd = rsqrtf(var + 1e-5f);

    const int c = t * 4;
    float4 g = *(const float4*)(gamma + c);
    float4 be = *(const float4*)(beta + c);
    float4 o;
    o.x = (v0 - mean) * rstd * g.x + be.x;
    o.y = (v1 - mean) * rstd * g.y + be.y;
    o.z = (v2 - mean) * rstd * g.z + be.z;
    o.w = (v3 - mean) * rstd * g.w + be.w;
    *(float4*)(out + base) = o;
}

extern "C" void kernel_launch(void* const* d_in, const int* in_sizes, int n_in,
                              void* d_out, int out_size, void* d_ws, size_t ws_size,
                              hipStream_t stream)
{
    const float* x     = (const float*)d_in[0];
    const float* Wq    = (const float*)d_in[1];
    const float* bq    = (const float*)d_in[2];
    const float* Wk    = (const float*)d_in[3];
    const float* bk    = (const float*)d_in[4];
    const float* Wv    = (const float*)d_in[5];
    const float* bv    = (const float*)d_in[6];
    const float* Wo    = (const float*)d_in[7];
    const float* bo    = (const float*)d_in[8];
    const float* gamma = (const float*)d_in[9];
    const float* beta  = (const float*)d_in[10];
    float* out = (float*)d_out;

    char* ws = (char*)d_ws;
    bf16* xb  = (bf16*)(ws + (size_t)0);
    bf16* Qb  = (bf16*)(ws + (size_t)33554432);   // also AO
    bf16* Kb  = (bf16*)(ws + (size_t)67108864);
    bf16* VT  = (bf16*)(ws + (size_t)100663296);
    bf16* Sb  = (bf16*)(ws + (size_t)134217728);  // also bf16 preLN
    bf16* Wqb = (bf16*)(ws + (size_t)201326592);
    bf16* Wkb = Wqb + 1048576;
    bf16* Wvb = Wkb + 1048576;
    bf16* Wob = Wvb + 1048576;

    // 1) casts
    cast_f32_bf16<<<16384, 256, 0, stream>>>(x, xb, 16777216);
    cast_f32_bf16<<<1024, 256, 0, stream>>>(Wq, Wqb, 1048576);
    cast_f32_bf16<<<1024, 256, 0, stream>>>(Wk, Wkb, 1048576);
    cast_f32_bf16<<<1024, 256, 0, stream>>>(Wv, Wvb, 1048576);
    cast_f32_bf16<<<1024, 256, 0, stream>>>(Wo, Wob, 1048576);

    // 2) Q = xb@Wq^T + bq   [16384,1024]
    gemm_bt<<<dim3(8, 128, 1), 256, 0, stream>>>(
        xb, 1024, 0, Wqb, 1024, 0, (void*)Qb, 1024, 0, bq, 1, 1.0f, 0, 1024);
    // 3) K
    gemm_bt<<<dim3(8, 128, 1), 256, 0, stream>>>(
        xb, 1024, 0, Wkb, 1024, 0, (void*)Kb, 1024, 0, bk, 1, 1.0f, 0, 1024);
    // 4) VT = Wv@xb^T + bv(row)   [1024,16384]
    gemm_bt<<<dim3(128, 8, 1), 256, 0, stream>>>(
        Wvb, 1024, 0, xb, 1024, 0, (void*)VT, 16384, 0, bv, 2, 1.0f, 0, 1024);
    // 5) scores = Q@K^T / 32   per batch, bf16 [2048,2048]
    gemm_bt<<<dim3(16, 16, 8), 256, 0, stream>>>(
        Qb, 1024, 2097152, Kb, 1024, 2097152, (void*)Sb, 2048, 4194304,
        nullptr, 0, 0.03125f, 0, 1024);
    // 6) softmax in place
    softmax2048<<<16384, 256, 0, stream>>>(Sb);
    // 7) AO = P@VT^T  (per batch; VT batch slice = columns b*2048..; into Qb)
    gemm_bt<<<dim3(8, 16, 8), 256, 0, stream>>>(
        Sb, 2048, 4194304, VT, 16384, 2048, (void*)Qb, 1024, 2097152,
        nullptr, 0, 1.0f, 0, 2048);
    // 8) preLN = AO@Wo^T + bo  (bf16, into Sb region)
    gemm_bt<<<dim3(8, 128, 1), 256, 0, stream>>>(
        Qb, 1024, 0, Wob, 1024, 0, (void*)Sb, 1024, 0, bo, 1, 1.0f, 0, 1024);
    // 9) LayerNorm(pre + x)
    ln_res<<<16384, 256, 0, stream>>>((const bf16*)Sb, x, gamma, beta, out);
}

// Round 5
// 451.170 us; speedup vs baseline: 1.6371x; 1.2855x over previous
//
#include <hip/hip_runtime.h>
#include <hip/hip_bf16.h>
#include <math.h>

// SelfAttentionLayer: B=8,S=2048,D=1024 (fp32 interface).
// R5: all GEMMs moved to MX-fp8 (OCP e4m3, unit scales 0x7F) using
//   v_mfma_scale_f32_32x32x64_f8f6f4 (the only large-K fp8 MFMA). BK=64,
//   block 128x128, wave 64x64 as 2x2 of 32x32 MFMAs. 2x MFMA rate + half
//   staging/LDS bytes vs bf16 (R4 accounting: no pipe >50%, serialization-
//   bound -> raise FLOPs per serialized iter 4x).
//   Numerics: residual+LN stay fp32; P scaled x256 pre-fp8 (subnormal floor),
//   AO x16; unscaled in epilogues. preLN bf16.
// Kept: XCD chunk swizzle, tbuf + raw s_barrier + vmcnt(4), XOR bank swizzle.

typedef __bf16 bf16;
typedef unsigned char u8;
typedef __attribute__((ext_vector_type(8))) __bf16 bf16x8;
typedef __attribute__((ext_vector_type(4))) __bf16 bf16x4;
typedef __attribute__((ext_vector_type(8))) int i32x8;
typedef __attribute__((ext_vector_type(16))) float f32x16;

__device__ __forceinline__ void async16(const u8* g, u8* l) {
    __builtin_amdgcn_global_load_lds(
        (const __attribute__((address_space(1))) void*)g,
        (__attribute__((address_space(3))) void*)l, 16, 0, 0);
}

// s_waitcnt imm: bits[3:0] vmcnt, [6:4] expcnt, [11:8] lgkmcnt
#define WAITCNT_VM(n) __builtin_amdgcn_s_waitcnt((15 << 8) | (7 << 4) | (n))

__device__ __forceinline__ u8 to_fp8(float v) {
    return (u8)(__builtin_amdgcn_cvt_pk_fp8_f32(v, v, 0, 0) & 0xFF);
}

__global__ __launch_bounds__(256) void cast_f32_fp8(
    const float* __restrict__ in, u8* __restrict__ out, int n)
{
    int i = (blockIdx.x * 256 + threadIdx.x) * 8;
    if (i >= n) return;
    float4 a = *(const float4*)(in + i);
    float4 b = *(const float4*)(in + i + 4);
    int lo = __builtin_amdgcn_cvt_pk_fp8_f32(a.x, a.y, 0, 0);
    lo = __builtin_amdgcn_cvt_pk_fp8_f32(a.z, a.w, lo, 1);
    int hi = __builtin_amdgcn_cvt_pk_fp8_f32(b.x, b.y, 0, 0);
    hi = __builtin_amdgcn_cvt_pk_fp8_f32(b.z, b.w, hi, 1);
    int2 o = { lo, hi };
    *(int2*)(out + i) = o;
}

// C[m,n] = scale * sum_k A[m,k]*B[n,k] (+bias); A:[M,K] lda, B:[N,K] ldb, fp8.
// bias_mode: 0 none, 1 bias[n], 2 bias[m]. c_mode: 0 bf16 out, 1 fp8 out.
// grid (N/128, M/128, batch), 256 thr = 4 waves, wave=64x64 (2x2 of 32x32x64).
__global__ __launch_bounds__(256) void gemm_f8(
    const u8* __restrict__ A, long lda, long sA,
    const u8* __restrict__ B, long ldb, long sB,
    void* __restrict__ Cv, long ldc, long sC,
    const float* __restrict__ bias, int bias_mode,
    float scale, int c_mode, int K)
{
    __shared__ u8 lds[3][16384];   // 3 stages x (A 8KB | B 8KB)

    // XCD chunk swizzle: flat%8 is the XCD round-robin -> give each XCD a
    // contiguous flat range for L2 tile reuse.
    const int gx = gridDim.x, gy = gridDim.y;
    const int slice = gx * gy;
    const int total = slice * gridDim.z;
    int flat = ((int)blockIdx.z * gy + (int)blockIdx.y) * gx + (int)blockIdx.x;
    if ((total & 7) == 0)
        flat = (flat & 7) * (total >> 3) + (flat >> 3);
    const int bz = flat / slice;
    const int rem = flat - bz * slice;
    const int by = rem / gx;
    const int bx = rem - by * gx;

    const int tid = threadIdx.x;
    const long tM = (long)by * 128;
    const long tN = (long)bx * 128;
    A += (long)bz * sA;
    B += (long)bz * sB;

    // staging: thread -> (row = tid/4, chunk pos = tid%4); LDS dst is
    // lane-contiguous tid*16 (global_load_lds requirement). Bank swizzle:
    // LDS pos p holds global 16B chunk p^(row&3) (64B rows -> XOR spreads
    // ds_read_b128 across all 32 banks; (row+64)&3 == row&3 so same ca).
    const int ra = tid >> 2;
    const int posc = tid & 3;
    const int ca = (posc ^ (ra & 3)) * 16;
    const u8* ga0 = A + (tM + ra) * lda + ca;
    const u8* ga1 = ga0 + 64 * lda;
    const u8* gb0 = B + (tN + ra) * ldb + ca;
    const u8* gb1 = gb0 + 64 * ldb;
    const int lo0 = tid * 16;           // A rows 0..63
    const int lo1 = 4096 + tid * 16;    // A rows 64..127
    const int lo2 = 8192 + tid * 16;    // B rows 0..63
    const int lo3 = 12288 + tid * 16;   // B rows 64..127

    const int w = tid >> 6, lane = tid & 63;
    const int wm = (w & 1) * 64, wn = (w >> 1) * 64;
    const int r32 = lane & 31, kh = lane >> 5;   // kh: which 32-byte K-half

    f32x16 acc[2][2] = {};

    const int iters = K >> 6;

    // prologue: batches 0,1 -> 8 outstanding vmem
    {
        u8* p0 = lds[0];
        async16(ga0, p0 + lo0); async16(ga1, p0 + lo1);
        async16(gb0, p0 + lo2); async16(gb1, p0 + lo3);
        u8* p1 = lds[1];
        async16(ga0 + 64, p1 + lo0); async16(ga1 + 64, p1 + lo1);
        async16(gb0 + 64, p1 + lo2); async16(gb1 + 64, p1 + lo3);
    }

    // fragment LDS offsets (A rows wm+0/+32, B rows wn+0/+32; chunks kh*2,kh*2+1)
    const int rowA0 = wm + r32, rowA1 = wm + 32 + r32;
    const int rowB0 = wn + r32, rowB1 = wn + 32 + r32;
    const int c0 = kh * 2, c1 = kh * 2 + 1;
    const int offA0q0 = rowA0 * 64 + ((c0 ^ (rowA0 & 3)) << 4);
    const int offA0q1 = rowA0 * 64 + ((c1 ^ (rowA0 & 3)) << 4);
    const int offA1q0 = rowA1 * 64 + ((c0 ^ (rowA1 & 3)) << 4);
    const int offA1q1 = rowA1 * 64 + ((c1 ^ (rowA1 & 3)) << 4);
    const int offB0q0 = 8192 + rowB0 * 64 + ((c0 ^ (rowB0 & 3)) << 4);
    const int offB0q1 = 8192 + rowB0 * 64 + ((c1 ^ (rowB0 & 3)) << 4);
    const int offB1q0 = 8192 + rowB1 * 64 + ((c0 ^ (rowB1 & 3)) << 4);
    const int offB1q1 = 8192 + rowB1 * 64 + ((c1 ^ (rowB1 & 3)) << 4);

    int cur = 0;
    for (int it = 0; it < iters; ++it) {
        if (it + 1 < iters) WAITCNT_VM(4);
        else WAITCNT_VM(0);
        __builtin_amdgcn_s_barrier();

        if (it + 2 < iters) {
            int nb = cur + 2; if (nb >= 3) nb -= 3;
            u8* p = lds[nb];
            const long ko = (long)(it + 2) << 6;
            async16(ga0 + ko, p + lo0); async16(ga1 + ko, p + lo1);
            async16(gb0 + ko, p + lo2); async16(gb1 + ko, p + lo3);
        }

        const u8* curb = lds[cur];
        union F { i32x8 v; int4 q[2]; };
        F a0, a1, b0, b1;
        a0.q[0] = *(const int4*)&curb[offA0q0];
        a0.q[1] = *(const int4*)&curb[offA0q1];
        a1.q[0] = *(const int4*)&curb[offA1q0];
        a1.q[1] = *(const int4*)&curb[offA1q1];
        b0.q[0] = *(const int4*)&curb[offB0q0];
        b0.q[1] = *(const int4*)&curb[offB0q1];
        b1.q[0] = *(const int4*)&curb[offB1q0];
        b1.q[1] = *(const int4*)&curb[offB1q1];

        // fmt 0 = OCP fp8 e4m3; scales 0x7F (=2^0) in every byte, opsel 0
        acc[0][0] = __builtin_amdgcn_mfma_scale_f32_32x32x64_f8f6f4(
            a0.v, b0.v, acc[0][0], 0, 0, 0, 0x7F7F7F7F, 0, 0x7F7F7F7F);
        acc[0][1] = __builtin_amdgcn_mfma_scale_f32_32x32x64_f8f6f4(
            a0.v, b1.v, acc[0][1], 0, 0, 0, 0x7F7F7F7F, 0, 0x7F7F7F7F);
        acc[1][0] = __builtin_amdgcn_mfma_scale_f32_32x32x64_f8f6f4(
            a1.v, b0.v, acc[1][0], 0, 0, 0, 0x7F7F7F7F, 0, 0x7F7F7F7F);
        acc[1][1] = __builtin_amdgcn_mfma_scale_f32_32x32x64_f8f6f4(
            a1.v, b1.v, acc[1][1], 0, 0, 0, 0x7F7F7F7F, 0, 0x7F7F7F7F);

        if (++cur >= 3) cur = 0;
    }

    // epilogue: 32x32 C/D layout col=lane&31, row=(reg&3)+8*(reg>>2)+4*kh
    // [m74/m101; dtype-independent m121-128]
#pragma unroll
    for (int i = 0; i < 2; i++) {
#pragma unroll
        for (int j = 0; j < 2; j++) {
            const long gn = tN + wn + j * 32 + r32;
            const float bn = (bias_mode == 1) ? bias[gn] : 0.0f;
#pragma unroll
            for (int reg = 0; reg < 16; reg++) {
                const int rowf = (reg & 3) + 8 * (reg >> 2) + 4 * kh;
                const long gm = tM + wm + i * 32 + rowf;
                float v = acc[i][j][reg] * scale + bn;
                if (bias_mode == 2) v += bias[gm];
                if (c_mode == 0)
                    ((bf16*)Cv + (long)bz * sC)[gm * ldc + gn] = (bf16)v;
                else
                    ((u8*)Cv + (long)bz * sC)[gm * ldc + gn] = to_fp8(v);
            }
        }
    }
}

// softmax over rows of 2048 bf16 scores -> fp8 P scaled x256
__global__ __launch_bounds__(256) void softmax_f8(
    const bf16* __restrict__ S, u8* __restrict__ P)
{
    const long row = blockIdx.x;
    const bf16* p = S + row * 2048;
    const int t = threadIdx.x;

    bf16x8 v = *(const bf16x8*)(p + t * 8);
    float f[8];
    float m = -3.0e38f;
#pragma unroll
    for (int i = 0; i < 8; i++) { f[i] = (float)v[i]; m = fmaxf(m, f[i]); }
    for (int o = 32; o; o >>= 1) m = fmaxf(m, __shfl_down(m, o));

    __shared__ float sm[4], ssum[4];
    if ((t & 63) == 0) sm[t >> 6] = m;
    __syncthreads();
    m = fmaxf(fmaxf(sm[0], sm[1]), fmaxf(sm[2], sm[3]));

    float s = 0.0f;
#pragma unroll
    for (int i = 0; i < 8; i++) { f[i] = __expf(f[i] - m); s += f[i]; }
    for (int o = 32; o; o >>= 1) s += __shfl_down(s, o);
    if ((t & 63) == 0) ssum[t >> 6] = s;
    __syncthreads();
    s = ssum[0] + ssum[1] + ssum[2] + ssum[3];

    const float c = 256.0f / s;   // x256: keep P out of fp8 subnormal range
    int lo = __builtin_amdgcn_cvt_pk_fp8_f32(f[0] * c, f[1] * c, 0, 0);
    lo = __builtin_amdgcn_cvt_pk_fp8_f32(f[2] * c, f[3] * c, lo, 1);
    int hi = __builtin_amdgcn_cvt_pk_fp8_f32(f[4] * c, f[5] * c, 0, 0);
    hi = __builtin_amdgcn_cvt_pk_fp8_f32(f[6] * c, f[7] * c, hi, 1);
    int2 o = { lo, hi };
    *(int2*)(P + row * 2048 + t * 8) = o;
}

// out = LN(pre + x) * gamma + beta; pre bf16, x fp32; rows of 1024
__global__ __launch_bounds__(256) void ln_res(
    const bf16* __restrict__ pre, const float* __restrict__ x,
    const float* __restrict__ gamma, const float* __restrict__ beta,
    float* __restrict__ out)
{
    const long row = blockIdx.x;
    const int t = threadIdx.x;
    const long base = row * 1024 + t * 4;

    bf16x4 a = *(const bf16x4*)(pre + base);
    float4 b = *(const float4*)(x + base);
    float v0 = (float)a[0] + b.x, v1 = (float)a[1] + b.y;
    float v2 = (float)a[2] + b.z, v3 = (float)a[3] + b.w;

    float s = v0 + v1 + v2 + v3;
    float q = v0 * v0 + v1 * v1 + v2 * v2 + v3 * v3;
    for (int o = 32; o; o >>= 1) { s += __shfl_down(s, o); q += __shfl_down(q, o); }

    __shared__ float ls[4], lq[4];
    if ((t & 63) == 0) { ls[t >> 6] = s; lq[t >> 6] = q; }
    __syncthreads();
    s = ls[0] + ls[1] + ls[2] + ls[3];
    q = lq[0] + lq[1] + lq[2] + lq[3];

    const float mean = s * (1.0f / 1024.0f);
    const float var = q * (1.0f / 1024.0f) - mean * mean;
    const float rstd = rsqrtf(var + 1e-5f);

    const int c = t * 4;
    float4 g = *(const float4*)(gamma + c);
    float4 be = *(const float4*)(beta + c);
    float4 o;
    o.x = (v0 - mean) * rstd * g.x + be.x;
    o.y = (v1 - mean) * rstd * g.y + be.y;
    o.z = (v2 - mean) * rstd * g.z + be.z;
    o.w = (v3 - mean) * rstd * g.w + be.w;
    *(float4*)(out + base) = o;
}

extern "C" void kernel_launch(void* const* d_in, const int* in_sizes, int n_in,
                              void* d_out, int out_size, void* d_ws, size_t ws_size,
                              hipStream_t stream)
{
    const float* x     = (const float*)d_in[0];
    const float* Wq    = (const float*)d_in[1];
    const float* bq    = (const float*)d_in[2];
    const float* Wk    = (const float*)d_in[3];
    const float* bk    = (const float*)d_in[4];
    const float* Wv    = (const float*)d_in[5];
    const float* bv    = (const float*)d_in[6];
    const float* Wo    = (const float*)d_in[7];
    const float* bo    = (const float*)d_in[8];
    const float* gamma = (const float*)d_in[9];
    const float* beta  = (const float*)d_in[10];
    float* out = (float*)d_out;

    char* ws = (char*)d_ws;
    u8* x8  = (u8*)(ws + (size_t)0);          // 16 MB [16384,1024]
    u8* Q8  = (u8*)(ws + (size_t)16777216);   // 16 MB (reused as AO8)
    u8* K8  = (u8*)(ws + (size_t)33554432);   // 16 MB
    u8* VT8 = (u8*)(ws + (size_t)50331648);   // 16 MB [1024,16384]
    u8* P8  = (u8*)(ws + (size_t)67108864);   // 32 MB [8,2048,2048]
    bf16* Sb = (bf16*)(ws + (size_t)104857600); // 64 MB scores; preLN reuse
    u8* Wq8 = (u8*)(ws + (size_t)176160768);
    u8* Wk8 = Wq8 + 1048576;
    u8* Wv8 = Wk8 + 1048576;
    u8* Wo8 = Wv8 + 1048576;

    // casts
    cast_f32_fp8<<<8192, 256, 0, stream>>>(x, x8, 16777216);
    cast_f32_fp8<<<512, 256, 0, stream>>>(Wq, Wq8, 1048576);
    cast_f32_fp8<<<512, 256, 0, stream>>>(Wk, Wk8, 1048576);
    cast_f32_fp8<<<512, 256, 0, stream>>>(Wv, Wv8, 1048576);
    cast_f32_fp8<<<512, 256, 0, stream>>>(Wo, Wo8, 1048576);

    // Q8 = x8@Wq8^T + bq  (fp8 out)
    gemm_f8<<<dim3(8, 128, 1), 256, 0, stream>>>(
        x8, 1024, 0, Wq8, 1024, 0, (void*)Q8, 1024, 0, bq, 1, 1.0f, 1, 1024);
    // K8
    gemm_f8<<<dim3(8, 128, 1), 256, 0, stream>>>(
        x8, 1024, 0, Wk8, 1024, 0, (void*)K8, 1024, 0, bk, 1, 1.0f, 1, 1024);
    // VT8 = Wv8@x8^T + bv(row)  [1024,16384] fp8
    gemm_f8<<<dim3(128, 8, 1), 256, 0, stream>>>(
        Wv8, 1024, 0, x8, 1024, 0, (void*)VT8, 16384, 0, bv, 2, 1.0f, 1, 1024);
    // scores (bf16) = Q8@K8^T / 32, per batch
    gemm_f8<<<dim3(16, 16, 8), 256, 0, stream>>>(
        Q8, 1024, 2097152, K8, 1024, 2097152, (void*)Sb, 2048, 4194304,
        nullptr, 0, 0.03125f, 0, 1024);
    // P8 = softmax(scores) * 256  (fp8)
    softmax_f8<<<16384, 256, 0, stream>>>(Sb, P8);
    // AO8 = (P8@VT8^T) * 16/256  -> stored AO = 16*AO_true (into Q8)
    gemm_f8<<<dim3(8, 16, 8), 256, 0, stream>>>(
        P8, 2048, 4194304, VT8, 16384, 2048, (void*)Q8, 1024, 2097152,
        nullptr, 0, 0.0625f, 1, 2048);
    // preLN (bf16, into Sb) = AO8@Wo8^T * (1/16) + bo
    gemm_f8<<<dim3(8, 128, 1), 256, 0, stream>>>(
        Q8, 1024, 0, Wo8, 1024, 0, (void*)Sb, 1024, 0, bo, 1, 0.0625f, 0, 1024);
    // out = LN(pre + x)
    ln_res<<<16384, 256, 0, stream>>>((const bf16*)Sb, x, gamma, beta, out);
}